// Round 4
// baseline (673.832 us; speedup 1.0000x reference)
//
#include <hip/hip_runtime.h>
#include <hip/hip_bf16.h>
#include <math.h>

// Problem constants
#define B_    32
#define CDD_  5
#define HIS_  100
#define S_    20
#define L_    3
#define F_    150
#define K_    18
#define RDIM_ 256
#define ROWE_ 9000           // S*L*F
#define NBC_  160            // B*CDD

typedef __attribute__((ext_vector_type(8))) short short8;
typedef __attribute__((ext_vector_type(4))) float f32x4;
typedef __attribute__((ext_vector_type(2))) float f32x2;

// RNE float->bf16 (no NaN inputs here)
static __device__ __forceinline__ unsigned short f2bf(float x) {
  union { float f; unsigned u; } v; v.f = x;
  unsigned r = v.u + 0x7fffu + ((v.u >> 16) & 1u);
  return (unsigned short)(r >> 16);
}

static __device__ __forceinline__ unsigned pack2bf(float a, float b) {
  return (unsigned)f2bf(a) | ((unsigned)f2bf(b) << 16);
}

// ---------------------------------------------------------------------------
// Kernel A: attention + stable top-K. grid=160 blocks x 256 threads.
// Also performs the conv-weight transposes (prep duty folded in), zero-inits
// the score accumulator and the per-b softmax completion counters.
// ---------------------------------------------------------------------------
__global__ __launch_bounds__(256) void attn_topk_kernel(
    const int* __restrict__ cdd_id, const int* __restrict__ his_id,
    const float* __restrict__ repr, int* __restrict__ gid,
    float* __restrict__ score, int* __restrict__ scnt,
    const float* __restrict__ w1, const float* __restrict__ w2,
    float* __restrict__ w1t, float* __restrict__ w2t) {
  int bc = blockIdx.x;          // 0..159
  int b  = bc / CDD_;
  int tid = threadIdx.x, lane = tid & 63, wave = tid >> 6;

  // prep duty: weight transposes, distributed over the grid
  int gidx = bc * 256 + tid;
  if (gidx < 2592) {
    int oc = gidx / 81, j = gidx % 81;
    w1t[j * 32 + oc] = w1[gidx];
  } else if (gidx < 2592 + 13824) {
    int i2 = gidx - 2592;
    int oc = i2 / 864, r = i2 % 864;
    w2t[r * 16 + oc] = w2[i2];
  }

  __shared__ float cddv[RDIM_];
  __shared__ float sattn[128];
  int cid = cdd_id[bc];
  cddv[tid] = repr[(size_t)cid * RDIM_ + tid];
  if (tid < 28) sattn[100 + tid] = -INFINITY;
  __syncthreads();

  float4 cv = *(const float4*)(cddv + lane * 4);
  for (int h = wave; h < HIS_; h += 4) {
    const float4* row = (const float4*)(repr + (size_t)his_id[b * HIS_ + h] * RDIM_);
    float4 rv = row[lane];
    float p = cv.x * rv.x;
    p = fmaf(cv.y, rv.y, p);
    p = fmaf(cv.z, rv.z, p);
    p = fmaf(cv.w, rv.w, p);
    #pragma unroll
    for (int off = 32; off >= 1; off >>= 1) p += __shfl_xor(p, off);
    if (lane == 0) sattn[h] = p;
  }
  __syncthreads();

  if (wave == 0) {
    float v0 = sattn[lane], v1 = sattn[lane + 64];
    for (int k = 0; k < K_; k++) {
      float bv; int bi;
      if (v1 > v0) { bv = v1; bi = lane + 64; } else { bv = v0; bi = lane; }
      #pragma unroll
      for (int off = 32; off >= 1; off >>= 1) {
        float ov = __shfl_xor(bv, off);
        int   oi = __shfl_xor(bi, off);
        if (ov > bv || (ov == bv && oi < bi)) { bv = ov; bi = oi; }
      }
      if (lane == 0) gid[bc * K_ + k] = his_id[b * HIS_ + bi];
      if (bi == lane)      v0 = -INFINITY;
      if (bi == lane + 64) v1 = -INFINITY;
    }
  }
  if (tid == 0) {
    score[bc] = 0.f;
    if (bc < B_) scnt[bc] = 0;
  }
}

// ---------------------------------------------------------------------------
// Kernel B: fusion einsum via bf16 MFMA. grid = 2880 blocks (b,c,k), 256 thr.
// Per l: C[20x20] = A[20x150] x B[20x150]^T, as 2x2 tiles of 16x16 with
// 5 K-steps of 32 (K padded 150->160, M/N padded 20->32).
// XCD-colocating swizzle + float4 staging + pad-only zero-init (R1-verified).
// ---------------------------------------------------------------------------
__global__ __launch_bounds__(256) void fusion_kernel(
    const int* __restrict__ cdd_id, const int* __restrict__ gid,
    const float* __restrict__ emb, float* __restrict__ x1) {
  // XCD swizzle: 2880 blocks, 8 XCDs, 360 per XCD chunk (360 % 18 == 0 so
  // each chunk holds whole bc groups).
  int bck = (blockIdx.x & 7) * 360 + (blockIdx.x >> 3);
  int bc = bck / K_, k = bck % K_;
  __shared__ unsigned short a_sh[3 * 32 * 160];   // 30 KB
  __shared__ unsigned short b_sh[3 * 32 * 160];   // 30 KB
  int tid = threadIdx.x;

  unsigned* az = (unsigned*)a_sh;
  unsigned* bz = (unsigned*)b_sh;
  // zero only the K-pad (f2 index 75..79) for all 96 rows
  for (int i = tid; i < 480; i += 256) {
    int l = i / 160, r = i % 160;
    int srow = r / 5, j = r % 5;
    int idx = (l * 32 + srow) * 80 + 75 + j;
    az[idx] = 0u; bz[idx] = 0u;
  }

  const float* crow = emb + (size_t)cdd_id[bc] * ROWE_;
  const float* hrow = emb + (size_t)gid[bck] * ROWE_;
  // 16B/lane staging: 2250 float4 per row
  for (int p = tid; p < 2250; p += 256) {
    int e0 = p * 4;
    int s0 = e0 / 450, r0 = e0 % 450;
    int l0 = r0 / 150, f0 = r0 % 150;
    int e2 = e0 + 2;
    int s2 = e2 / 450, r2 = e2 % 450;
    int l2 = r2 / 150, f2 = r2 % 150;
    float4 cv = *(const float4*)(crow + e0);
    float4 hv = *(const float4*)(hrow + e0);
    int d0 = (l0 * 32 + s0) * 80 + (f0 >> 1);
    int d2 = (l2 * 32 + s2) * 80 + (f2 >> 1);
    az[d0] = pack2bf(cv.x, cv.y);
    az[d2] = pack2bf(cv.z, cv.w);
    bz[d0] = pack2bf(hv.x, hv.y);
    bz[d2] = pack2bf(hv.z, hv.w);
  }
  __syncthreads();

  int wave = tid >> 6, lane = tid & 63;
  int m15 = lane & 15, quad = lane >> 4;
  const float scale = 0.0816496580927726f;    // 1/sqrt(150)
  for (int j = wave; j < 12; j += 4) {        // j = l*4 + mt*2 + nt
    int l = j >> 2, mt = (j >> 1) & 1, nt = j & 1;
    f32x4 acc = {0.f, 0.f, 0.f, 0.f};
    int abase = (l * 32 + mt * 16 + m15) * 160 + quad * 8;
    int bbase = (l * 32 + nt * 16 + m15) * 160 + quad * 8;
    #pragma unroll
    for (int kb = 0; kb < 5; kb++) {
      short8 af = *(const short8*)(a_sh + abase + kb * 32);
      short8 bf = *(const short8*)(b_sh + bbase + kb * 32);
      acc = __builtin_amdgcn_mfma_f32_16x16x32_bf16(af, bf, acc, 0, 0, 0);
    }
    int t = nt * 16 + m15;
    if (t < 20) {
      size_t base = ((size_t)(bc * 3 + l) * K_ + k) * 400;
      #pragma unroll
      for (int reg = 0; reg < 4; reg++) {
        int s = mt * 16 + quad * 4 + reg;
        if (s < 20) x1[base + s * 20 + t] = acc[reg] * scale;
      }
    }
  }
}

// ---------------------------------------------------------------------------
// Kernel C: conv1(3->32) + bias + ReLU + maxpool. grid = 960, 320 thr.
// Job = (dl, h, pw): the 3 w-positions of one pool cell computed by ONE
// thread. Per (c,kd,kh): 5 overlapping tile reads serve all 3 positions
// (vs 9), weights reused across the triple, local w-max then 1/3 the LDS
// atomics. Tap summation order per output is unchanged -> bit-identical.
// ---------------------------------------------------------------------------
__global__ __launch_bounds__(320) void conv1_kernel(
    const float* __restrict__ x1, const float* __restrict__ w1t,
    const float* __restrict__ b1, float* __restrict__ p1) {
  int bid = blockIdx.x;
  int n = bid / 6, dp = bid % 6;
  __shared__ float tile[3 * 5 * 22 * 22];     // 7260 floats, padded input slab
  __shared__ unsigned pooled[32 * 36];        // 32 oc x (6x6)
  int tid = threadIdx.x;

  for (int i = tid; i < 7260; i += 320) {
    int c = i / 2420; int r = i % 2420;
    int dd = r / 484; r %= 484;
    int hh = r / 22, ww = r % 22;
    int d = dp * 3 + dd - 1, h = hh - 1, w = ww - 1;
    float v = 0.f;
    if (d >= 0 && d < 18 && h >= 0 && h < 20 && w >= 0 && w < 20)
      v = x1[((size_t)(n * 3 + c) * K_ + d) * 400 + h * 20 + w];
    tile[i] = v;
  }
  for (int i = tid; i < 1152; i += 320) pooled[i] = 0u;
  __syncthreads();

  const f32x2* b1v = (const f32x2*)b1;
  // 324 jobs: dl(3) x h(18) x pw(6)
  for (int job = tid; job < 324; job += 320) {
    int dl = job / 108; int r = job % 108;
    int h = r / 6, pw = r % 6;
    int w0 = pw * 3;
    f32x2 acc[3][16];
    #pragma unroll
    for (int j = 0; j < 3; j++)
      #pragma unroll
      for (int i = 0; i < 16; i++) acc[j][i] = b1v[i];

    for (int c = 0; c < 3; c++) {
      const float* tc = tile + (c * 5 + dl) * 484 + h * 22 + w0;
      const float* wc = w1t + c * 27 * 32;
      #pragma unroll
      for (int kd = 0; kd < 3; kd++)
        #pragma unroll
        for (int kh = 0; kh < 3; kh++) {
          const float* tr = tc + kd * 484 + kh * 22;
          float rv[5];
          #pragma unroll
          for (int q = 0; q < 5; q++) rv[q] = tr[q];
          #pragma unroll
          for (int kw = 0; kw < 3; kw++) {
            const f32x2* wp = (const f32x2*)(wc + (kd * 9 + kh * 3 + kw) * 32);
            #pragma unroll
            for (int i = 0; i < 16; i++) {
              f32x2 wv = wp[i];
              #pragma unroll
              for (int j = 0; j < 3; j++) {
                f32x2 iv2 = {rv[j + kw], rv[j + kw]};
                acc[j][i] = __builtin_elementwise_fma(iv2, wv, acc[j][i]);
              }
            }
          }
        }
    }
    int pbase = (h / 3) * 6 + pw;
    #pragma unroll
    for (int i = 0; i < 16; i++) {
      float mx = fmaxf(acc[0][i].x, fmaxf(acc[1][i].x, acc[2][i].x));
      float my = fmaxf(acc[0][i].y, fmaxf(acc[1][i].y, acc[2][i].y));
      atomicMax(&pooled[(2 * i) * 36 + pbase],     __float_as_uint(fmaxf(mx, 0.f)));
      atomicMax(&pooled[(2 * i + 1) * 36 + pbase], __float_as_uint(fmaxf(my, 0.f)));
    }
  }
  __syncthreads();
  for (int i = tid; i < 1152; i += 320) {
    int oc = i / 36; int r = i % 36;
    p1[(size_t)(n * 32 + oc) * 216 + dp * 36 + r] = __uint_as_float(pooled[i]);
  }
}

// ---------------------------------------------------------------------------
// Kernel D: conv2(32->16) + bias + ReLU + maxpool + LTR dot + (for the last
// finishing block of each b) the log_softmax epilogue. grid = 320.
// Completion tracked via device-scope counter scnt[b]; score adds are
// device-scope atomics, ordered by __threadfence.
// ---------------------------------------------------------------------------
__global__ __launch_bounds__(256) void conv2_kernel(
    const float* __restrict__ p1, const float* __restrict__ w2t,
    const float* __restrict__ b2, const float* __restrict__ lw,
    const float* __restrict__ lb, float* __restrict__ score,
    int* __restrict__ scnt, float* __restrict__ out) {
  int bid = blockIdx.x;
  int n = bid / 2, og = bid % 2;          // n = bc index 0..159
  __shared__ float tile[32 * 8 * 8 * 8];   // 64KB padded: [c][d+1][h+1][w+1]
  __shared__ unsigned pooled[64];          // 8 oc x 8 pooled pos
  int tid = threadIdx.x;

  for (int i = tid; i < 32 * 512; i += 256) tile[i] = 0.f;
  if (tid < 64) pooled[tid] = 0u;
  __syncthreads();
  for (int i = tid; i < 32 * 216; i += 256) {
    int c = i / 216; int r = i % 216;
    int d = r / 36; r %= 36;
    int h = r / 6, w = r % 6;
    tile[c * 512 + (d + 1) * 64 + (h + 1) * 8 + (w + 1)] =
        p1[(size_t)n * 32 * 216 + i];
  }
  __syncthreads();

  if (tid < 216) {
    int d = tid / 36; int r = tid % 36;
    int h = r / 6, w = r % 6;
    f32x2 acc[4];
    #pragma unroll
    for (int i = 0; i < 4; i++)
      acc[i] = (f32x2){b2[og * 8 + 2 * i], b2[og * 8 + 2 * i + 1]};
    for (int c = 0; c < 32; c++) {
      const float* tc = tile + c * 512 + d * 64 + h * 8 + w;  // window origin
      const float* wc = w2t + c * 27 * 16 + og * 8;
      #pragma unroll
      for (int kd = 0; kd < 3; kd++)
        #pragma unroll
        for (int kh = 0; kh < 3; kh++)
          #pragma unroll
          for (int kw = 0; kw < 3; kw++) {
            float iv = tc[kd * 64 + kh * 8 + kw];
            f32x2 ivv = {iv, iv};
            const f32x2* wp = (const f32x2*)(wc + (kd * 9 + kh * 3 + kw) * 16);
            #pragma unroll
            for (int i = 0; i < 4; i++)
              acc[i] = __builtin_elementwise_fma(ivv, wp[i], acc[i]);
          }
    }
    int pb = (d / 3) * 4 + (h / 3) * 2 + (w / 3);
    #pragma unroll
    for (int i = 0; i < 4; i++) {
      atomicMax(&pooled[(2 * i) * 8 + pb],     __float_as_uint(fmaxf(acc[i].x, 0.f)));
      atomicMax(&pooled[(2 * i + 1) * 8 + pb], __float_as_uint(fmaxf(acc[i].y, 0.f)));
    }
  }
  __syncthreads();

  if (tid < 64) {
    int oc = tid / 8, pb = tid % 8;
    float contrib = __uint_as_float(pooled[tid]) * lw[(og * 8 + oc) * 8 + pb];
    #pragma unroll
    for (int off = 32; off >= 1; off >>= 1) contrib += __shfl_xor(contrib, off);
    if (tid == 0) atomicAdd(&score[n], contrib);
  }

  // softmax epilogue: the 10th (last) finishing block of this b does it
  if (tid == 0) {
    __threadfence();
    int b = n / CDD_;
    int old = atomicAdd(&scnt[b], 1);
    if (old == 2 * CDD_ - 1) {
      __threadfence();
      float s[CDD_];
      float mx = -INFINITY;
      #pragma unroll
      for (int c = 0; c < CDD_; c++) {
        s[c] = score[b * CDD_ + c] + lb[0];
        mx = fmaxf(mx, s[c]);
      }
      float sum = 0.f;
      #pragma unroll
      for (int c = 0; c < CDD_; c++) sum += expf(s[c] - mx);
      float lse = mx + logf(sum);
      #pragma unroll
      for (int c = 0; c < CDD_; c++) out[b * CDD_ + c] = s[c] - lse;
    }
  }
}

// ---------------------------------------------------------------------------
extern "C" void kernel_launch(void* const* d_in, const int* in_sizes, int n_in,
                              void* d_out, int out_size, void* d_ws, size_t ws_size,
                              hipStream_t stream) {
  const int*   cdd_id = (const int*)d_in[0];
  const int*   his_id = (const int*)d_in[1];
  const float* repr   = (const float*)d_in[2];
  const float* emb    = (const float*)d_in[3];
  const float* w1     = (const float*)d_in[4];
  const float* b1     = (const float*)d_in[5];
  const float* w2     = (const float*)d_in[6];
  const float* b2     = (const float*)d_in[7];
  const float* lw     = (const float*)d_in[8];
  const float* lb     = (const float*)d_in[9];
  float* out = (float*)d_out;

  // workspace layout (~18.3 MB)
  char* ws = (char*)d_ws;
  int*   gid   = (int*)ws;                               // 2880 ints
  float* score = (float*)(ws + 11520);                   // 160 floats
  float* x1    = (float*)(ws + 12160);                   // 3,456,000 floats
  float* p1    = (float*)(ws + 12160 + 13824000);        // 1,105,920 floats
  float* w1t   = (float*)(ws + 12160 + 13824000 + 4423680);        // 2592 f
  float* w2t   = (float*)(ws + 12160 + 13824000 + 4423680 + 10368); // 13824 f
  int*   scnt  = (int*)(ws + 12160 + 13824000 + 4423680 + 10368 + 55296); // 32 i

  attn_topk_kernel<<<NBC_, 256, 0, stream>>>(cdd_id, his_id, repr, gid, score,
                                             scnt, w1, w2, w1t, w2t);
  fusion_kernel<<<NBC_ * K_, 256, 0, stream>>>(cdd_id, gid, emb, x1);
  conv1_kernel<<<NBC_ * 6, 320, 0, stream>>>(x1, w1t, b1, p1);
  conv2_kernel<<<NBC_ * 2, 256, 0, stream>>>(p1, w2t, b2, lw, lb, score, scnt, out);
}

// Round 5
// 602.623 us; speedup vs baseline: 1.1182x; 1.1182x over previous
//
#include <hip/hip_runtime.h>
#include <hip/hip_bf16.h>
#include <math.h>

// Problem constants
#define B_    32
#define CDD_  5
#define HIS_  100
#define S_    20
#define L_    3
#define F_    150
#define K_    18
#define RDIM_ 256
#define ROWE_ 9000           // S*L*F
#define NBC_  160            // B*CDD

typedef __attribute__((ext_vector_type(8))) short short8;
typedef __attribute__((ext_vector_type(4))) float f32x4;

// RNE float->bf16 (no NaN inputs here)
static __device__ __forceinline__ unsigned short f2bf(float x) {
  union { float f; unsigned u; } v; v.f = x;
  unsigned r = v.u + 0x7fffu + ((v.u >> 16) & 1u);
  return (unsigned short)(r >> 16);
}

static __device__ __forceinline__ unsigned pack2bf(float a, float b) {
  return (unsigned)f2bf(a) | ((unsigned)f2bf(b) << 16);
}

// ---------------------------------------------------------------------------
// Kernel A: attention + stable top-K. grid=160 blocks x 256 threads.
// Also performs the conv-weight transposes (prep duty folded in), zero-inits
// the score accumulator and the per-b softmax completion counters.
// ---------------------------------------------------------------------------
__global__ __launch_bounds__(256) void attn_topk_kernel(
    const int* __restrict__ cdd_id, const int* __restrict__ his_id,
    const float* __restrict__ repr, int* __restrict__ gid,
    float* __restrict__ score, int* __restrict__ scnt,
    const float* __restrict__ w1, const float* __restrict__ w2,
    float* __restrict__ w1t, float* __restrict__ w2t) {
  int bc = blockIdx.x;          // 0..159
  int b  = bc / CDD_;
  int tid = threadIdx.x, lane = tid & 63, wave = tid >> 6;

  // prep duty: weight transposes, distributed over the grid
  int gidx = bc * 256 + tid;
  if (gidx < 2592) {
    int oc = gidx / 81, j = gidx % 81;
    w1t[j * 32 + oc] = w1[gidx];
  } else if (gidx < 2592 + 13824) {
    int i2 = gidx - 2592;
    int oc = i2 / 864, r = i2 % 864;
    w2t[r * 16 + oc] = w2[i2];
  }

  __shared__ float cddv[RDIM_];
  __shared__ float sattn[128];
  int cid = cdd_id[bc];
  cddv[tid] = repr[(size_t)cid * RDIM_ + tid];
  if (tid < 28) sattn[100 + tid] = -INFINITY;
  __syncthreads();

  float4 cv = *(const float4*)(cddv + lane * 4);
  for (int h = wave; h < HIS_; h += 4) {
    const float4* row = (const float4*)(repr + (size_t)his_id[b * HIS_ + h] * RDIM_);
    float4 rv = row[lane];
    float p = cv.x * rv.x;
    p = fmaf(cv.y, rv.y, p);
    p = fmaf(cv.z, rv.z, p);
    p = fmaf(cv.w, rv.w, p);
    #pragma unroll
    for (int off = 32; off >= 1; off >>= 1) p += __shfl_xor(p, off);
    if (lane == 0) sattn[h] = p;
  }
  __syncthreads();

  if (wave == 0) {
    float v0 = sattn[lane], v1 = sattn[lane + 64];
    for (int k = 0; k < K_; k++) {
      float bv; int bi;
      if (v1 > v0) { bv = v1; bi = lane + 64; } else { bv = v0; bi = lane; }
      #pragma unroll
      for (int off = 32; off >= 1; off >>= 1) {
        float ov = __shfl_xor(bv, off);
        int   oi = __shfl_xor(bi, off);
        if (ov > bv || (ov == bv && oi < bi)) { bv = ov; bi = oi; }
      }
      if (lane == 0) gid[bc * K_ + k] = his_id[b * HIS_ + bi];
      if (bi == lane)      v0 = -INFINITY;
      if (bi == lane + 64) v1 = -INFINITY;
    }
  }
  if (tid == 0) {
    score[bc] = 0.f;
    if (bc < B_) scnt[bc] = 0;
  }
}

// ---------------------------------------------------------------------------
// Fusion helpers: staging one 9000-float row into bf16 LDS, and the
// verified MFMA 2x2-tile compute + guarded store for one k.
// ---------------------------------------------------------------------------
static __device__ __forceinline__ void stage_row_b(
    const float* __restrict__ row, unsigned* __restrict__ dst, int tid) {
  for (int p = tid; p < 2250; p += 256) {
    int e0 = p * 4;
    int s0 = e0 / 450, r0 = e0 % 450;
    int l0 = r0 / 150, f0 = r0 % 150;
    int e2 = e0 + 2;
    int s2 = e2 / 450, r2 = e2 % 450;
    int l2 = r2 / 150, f2 = r2 % 150;
    float4 v = *(const float4*)(row + e0);
    dst[(l0 * 32 + s0) * 80 + (f0 >> 1)] = pack2bf(v.x, v.y);
    dst[(l2 * 32 + s2) * 80 + (f2 >> 1)] = pack2bf(v.z, v.w);
  }
}

static __device__ __forceinline__ void mfma_tile_store(
    const unsigned short* __restrict__ a_sh,
    const unsigned short* __restrict__ b_sh,
    int wave, int m15, int quad, int bc, int k, float* __restrict__ x1) {
  const float scale = 0.0816496580927726f;    // 1/sqrt(150)
  for (int j = wave; j < 12; j += 4) {        // j = l*4 + mt*2 + nt
    int l = j >> 2, mt = (j >> 1) & 1, nt = j & 1;
    f32x4 acc = {0.f, 0.f, 0.f, 0.f};
    int abase = (l * 32 + mt * 16 + m15) * 160 + quad * 8;
    int bbase = (l * 32 + nt * 16 + m15) * 160 + quad * 8;
    #pragma unroll
    for (int kb = 0; kb < 5; kb++) {
      short8 af = *(const short8*)(a_sh + abase + kb * 32);
      short8 bf = *(const short8*)(b_sh + bbase + kb * 32);
      acc = __builtin_amdgcn_mfma_f32_16x16x32_bf16(af, bf, acc, 0, 0, 0);
    }
    int t = nt * 16 + m15;
    if (t < 20) {
      size_t base = ((size_t)(bc * 3 + l) * K_ + k) * 400;
      #pragma unroll
      for (int reg = 0; reg < 4; reg++) {
        int s = mt * 16 + quad * 4 + reg;
        if (s < 20) x1[base + s * 20 + t] = acc[reg] * scale;
      }
    }
  }
}

// ---------------------------------------------------------------------------
// Kernel B: fusion einsum via bf16 MFMA. grid = 1440 blocks = (bc, k-pair),
// 256 thr. Per l: C[20x20] = A[20x150] x B[20x150]^T, as 2x2 tiles of 16x16
// with 5 K-steps of 32 (K padded 150->160, M/N padded 20->32).
// k-pairing: the cdd row (A) is staged ONCE per two k's; B restaged between.
// XCD-colocating swizzle + float4 staging + pad-only zero-init (R1-verified).
// ---------------------------------------------------------------------------
__global__ __launch_bounds__(256) void fusion_kernel(
    const int* __restrict__ cdd_id, const int* __restrict__ gid,
    const float* __restrict__ emb, float* __restrict__ x1) {
  // XCD swizzle: 1440 blocks, 8 XCDs, 180 per chunk (180 % 9 == 0 so each
  // chunk holds whole bc groups -> cdd/his row re-fetches are L2-local).
  int lb = (blockIdx.x & 7) * 180 + (blockIdx.x >> 3);
  int bc = lb / 9, kp = lb % 9;
  int k0 = 2 * kp, k1 = 2 * kp + 1;
  __shared__ unsigned short a_sh[3 * 32 * 160];   // 30 KB
  __shared__ unsigned short b_sh[3 * 32 * 160];   // 30 KB
  int tid = threadIdx.x;

  unsigned* az = (unsigned*)a_sh;
  unsigned* bz = (unsigned*)b_sh;
  // zero only the K-pad (f2 index 75..79) for all 96 rows of both buffers;
  // B restaging never touches the pad, so it stays zero for k1 too.
  for (int i = tid; i < 480; i += 256) {
    int l = i / 160, r = i % 160;
    int srow = r / 5, j = r % 5;
    int idx = (l * 32 + srow) * 80 + 75 + j;
    az[idx] = 0u; bz[idx] = 0u;
  }

  // stage A (cdd row) and B(k0) in one shared-index loop (16B/lane loads)
  const float* crow  = emb + (size_t)cdd_id[bc] * ROWE_;
  const float* hrow0 = emb + (size_t)gid[bc * K_ + k0] * ROWE_;
  for (int p = tid; p < 2250; p += 256) {
    int e0 = p * 4;
    int s0 = e0 / 450, r0 = e0 % 450;
    int l0 = r0 / 150, f0 = r0 % 150;
    int e2 = e0 + 2;
    int s2 = e2 / 450, r2 = e2 % 450;
    int l2 = r2 / 150, f2 = r2 % 150;
    float4 cv = *(const float4*)(crow + e0);
    float4 hv = *(const float4*)(hrow0 + e0);
    int d0 = (l0 * 32 + s0) * 80 + (f0 >> 1);
    int d2 = (l2 * 32 + s2) * 80 + (f2 >> 1);
    az[d0] = pack2bf(cv.x, cv.y);
    az[d2] = pack2bf(cv.z, cv.w);
    bz[d0] = pack2bf(hv.x, hv.y);
    bz[d2] = pack2bf(hv.z, hv.w);
  }
  __syncthreads();

  int wave = tid >> 6, lane = tid & 63;
  int m15 = lane & 15, quad = lane >> 4;

  mfma_tile_store(a_sh, b_sh, wave, m15, quad, bc, k0, x1);
  __syncthreads();   // all b_sh reads done before restage

  const float* hrow1 = emb + (size_t)gid[bc * K_ + k1] * ROWE_;
  stage_row_b(hrow1, bz, tid);
  __syncthreads();

  mfma_tile_store(a_sh, b_sh, wave, m15, quad, bc, k1, x1);
}

// ---------------------------------------------------------------------------
// Kernel C: conv1(3->32) + bias + ReLU + maxpool, fused. grid = 960, 256 thr.
// Thread=position, acc[32] registers; inner loop = 1 LDS read broadcast into
// 32 FMAs with scalar-cached weights from w1t. (R1-verified form.)
// ---------------------------------------------------------------------------
__global__ __launch_bounds__(256) void conv1_kernel(
    const float* __restrict__ x1, const float* __restrict__ w1t,
    const float* __restrict__ b1, float* __restrict__ p1) {
  int bid = blockIdx.x;
  int n = bid / 6, dp = bid % 6;
  __shared__ float tile[3 * 5 * 22 * 22];     // 7260 floats, padded input slab
  __shared__ unsigned pooled[32 * 36];        // 32 oc x (6x6)
  int tid = threadIdx.x;

  for (int i = tid; i < 7260; i += 256) {
    int c = i / 2420; int r = i % 2420;
    int dd = r / 484; r %= 484;
    int hh = r / 22, ww = r % 22;
    int d = dp * 3 + dd - 1, h = hh - 1, w = ww - 1;
    float v = 0.f;
    if (d >= 0 && d < 18 && h >= 0 && h < 20 && w >= 0 && w < 20)
      v = x1[((size_t)(n * 3 + c) * K_ + d) * 400 + h * 20 + w];
    tile[i] = v;
  }
  for (int i = tid; i < 1152; i += 256) pooled[i] = 0u;
  __syncthreads();

  for (int pos = tid; pos < 972; pos += 256) {
    int dl = pos / 324; int r = pos % 324;
    int h = r / 18, w = r % 18;
    float acc[32];
    #pragma unroll
    for (int oc = 0; oc < 32; oc++) acc[oc] = b1[oc];

    for (int c = 0; c < 3; c++) {
      const float* tc = tile + (c * 5 + dl) * 484 + h * 22 + w;
      const float* wc = w1t + c * 27 * 32;
      #pragma unroll
      for (int kd = 0; kd < 3; kd++)
        #pragma unroll
        for (int kh = 0; kh < 3; kh++)
          #pragma unroll
          for (int kw = 0; kw < 3; kw++) {
            float iv = tc[kd * 484 + kh * 22 + kw];
            const float* wp = wc + (kd * 9 + kh * 3 + kw) * 32;
            #pragma unroll
            for (int oc = 0; oc < 32; oc++) acc[oc] = fmaf(iv, wp[oc], acc[oc]);
          }
    }
    int pbase = (h / 3) * 6 + (w / 3);
    #pragma unroll
    for (int oc = 0; oc < 32; oc++)
      atomicMax(&pooled[oc * 36 + pbase], __float_as_uint(fmaxf(acc[oc], 0.f)));
  }
  __syncthreads();
  for (int i = tid; i < 1152; i += 256) {
    int oc = i / 36; int r = i % 36;
    p1[(size_t)(n * 32 + oc) * 216 + dp * 36 + r] = __uint_as_float(pooled[i]);
  }
}

// ---------------------------------------------------------------------------
// Kernel D: conv2(32->16) + bias + ReLU + maxpool + LTR dot. grid = 320.
// Padded LDS tile [32][8][8][8]; acc[8] registers; scalar-broadcast weights.
// One float atomicAdd per block into score[n]. The 10th (last) finishing
// block of each b runs the log_softmax epilogue; score values are read back
// via atomicAdd(p, 0.f) to stay at the device coherence point (XCD-safe).
// ---------------------------------------------------------------------------
__global__ __launch_bounds__(256) void conv2_kernel(
    const float* __restrict__ p1, const float* __restrict__ w2t,
    const float* __restrict__ b2, const float* __restrict__ lw,
    const float* __restrict__ lb, float* __restrict__ score,
    int* __restrict__ scnt, float* __restrict__ out) {
  int bid = blockIdx.x;
  int n = bid / 2, og = bid % 2;
  __shared__ float tile[32 * 8 * 8 * 8];   // 64KB padded: [c][d+1][h+1][w+1]
  __shared__ unsigned pooled[64];          // 8 oc x 8 pooled pos
  int tid = threadIdx.x;

  for (int i = tid; i < 32 * 512; i += 256) tile[i] = 0.f;
  if (tid < 64) pooled[tid] = 0u;
  __syncthreads();
  for (int i = tid; i < 32 * 216; i += 256) {
    int c = i / 216; int r = i % 216;
    int d = r / 36; r %= 36;
    int h = r / 6, w = r % 6;
    tile[c * 512 + (d + 1) * 64 + (h + 1) * 8 + (w + 1)] =
        p1[(size_t)n * 32 * 216 + i];
  }
  __syncthreads();

  if (tid < 216) {
    int d = tid / 36; int r = tid % 36;
    int h = r / 6, w = r % 6;
    float acc[8];
    #pragma unroll
    for (int oc = 0; oc < 8; oc++) acc[oc] = b2[og * 8 + oc];
    for (int c = 0; c < 32; c++) {
      const float* tc = tile + c * 512 + d * 64 + h * 8 + w;  // window origin
      const float* wc = w2t + c * 27 * 16 + og * 8;
      #pragma unroll
      for (int kd = 0; kd < 3; kd++)
        #pragma unroll
        for (int kh = 0; kh < 3; kh++)
          #pragma unroll
          for (int kw = 0; kw < 3; kw++) {
            float iv = tc[kd * 64 + kh * 8 + kw];
            const float* wp = wc + (kd * 9 + kh * 3 + kw) * 16;
            #pragma unroll
            for (int oc = 0; oc < 8; oc++) acc[oc] = fmaf(iv, wp[oc], acc[oc]);
          }
    }
    int pb = (d / 3) * 4 + (h / 3) * 2 + (w / 3);
    #pragma unroll
    for (int oc = 0; oc < 8; oc++)
      atomicMax(&pooled[oc * 8 + pb], __float_as_uint(fmaxf(acc[oc], 0.f)));
  }
  __syncthreads();

  if (tid < 64) {
    int oc = tid / 8, pb = tid % 8;
    float contrib = __uint_as_float(pooled[tid]) * lw[(og * 8 + oc) * 8 + pb];
    #pragma unroll
    for (int off = 32; off >= 1; off >>= 1) contrib += __shfl_xor(contrib, off);
    if (tid == 0) atomicAdd(&score[n], contrib);
  }

  // log_softmax epilogue by the last finishing block of this b
  if (tid == 0) {
    __threadfence();
    int b = n / CDD_;
    int old = atomicAdd(&scnt[b], 1);
    if (old == 2 * CDD_ - 1) {
      float s[CDD_];
      float mx = -INFINITY;
      #pragma unroll
      for (int c = 0; c < CDD_; c++) {
        s[c] = atomicAdd(&score[b * CDD_ + c], 0.0f) + lb[0];
        mx = fmaxf(mx, s[c]);
      }
      float sum = 0.f;
      #pragma unroll
      for (int c = 0; c < CDD_; c++) sum += expf(s[c] - mx);
      float lse = mx + logf(sum);
      #pragma unroll
      for (int c = 0; c < CDD_; c++) out[b * CDD_ + c] = s[c] - lse;
    }
  }
}

// ---------------------------------------------------------------------------
extern "C" void kernel_launch(void* const* d_in, const int* in_sizes, int n_in,
                              void* d_out, int out_size, void* d_ws, size_t ws_size,
                              hipStream_t stream) {
  const int*   cdd_id = (const int*)d_in[0];
  const int*   his_id = (const int*)d_in[1];
  const float* repr   = (const float*)d_in[2];
  const float* emb    = (const float*)d_in[3];
  const float* w1     = (const float*)d_in[4];
  const float* b1     = (const float*)d_in[5];
  const float* w2     = (const float*)d_in[6];
  const float* b2     = (const float*)d_in[7];
  const float* lw     = (const float*)d_in[8];
  const float* lb     = (const float*)d_in[9];
  float* out = (float*)d_out;

  // workspace layout (~18.3 MB)
  char* ws = (char*)d_ws;
  int*   gid   = (int*)ws;                               // 2880 ints
  float* score = (float*)(ws + 11520);                   // 160 floats
  float* x1    = (float*)(ws + 12160);                   // 3,456,000 floats
  float* p1    = (float*)(ws + 12160 + 13824000);        // 1,105,920 floats
  float* w1t   = (float*)(ws + 12160 + 13824000 + 4423680);        // 2592 f
  float* w2t   = (float*)(ws + 12160 + 13824000 + 4423680 + 10368); // 13824 f
  int*   scnt  = (int*)(ws + 12160 + 13824000 + 4423680 + 10368 + 55296); // 32 i

  attn_topk_kernel<<<NBC_, 256, 0, stream>>>(cdd_id, his_id, repr, gid, score,
                                             scnt, w1, w2, w1t, w2t);
  fusion_kernel<<<NBC_ * 9, 256, 0, stream>>>(cdd_id, gid, emb, x1);
  conv1_kernel<<<NBC_ * 6, 256, 0, stream>>>(x1, w1t, b1, p1);
  conv2_kernel<<<NBC_ * 2, 256, 0, stream>>>(p1, w2t, b2, lw, lb, score, scnt, out);
}